// Round 1
// baseline (396.629 us; speedup 1.0000x reference)
//
#include <hip/hip_runtime.h>
#include <hip/hip_bf16.h>

// Problem: out = lecac_linear(relu(lecac_linear(x, W1, b1)), W2, b2)
//   x: [262144, 256] f32, W1: [512,256], b1: [512], W2: [256,512], b2: [256]
// Strategy: quantize weights to exact integer codes (bf16) once, then one fused
// MFMA kernel: h^T = W1q * x^T (h kept in LDS as bf16), out^T = W2q * h^T.

typedef __attribute__((ext_vector_type(8))) short bf16x8;
typedef __attribute__((ext_vector_type(4))) float f32x4;
typedef __attribute__((ext_vector_type(4))) unsigned short us4;

#define D_IN 256
#define D_HID 512
#define D_OUT 256
#define BM 64

__device__ __forceinline__ unsigned short f2bf(float f) {
  union { __hip_bfloat16 h; unsigned short u; } c;
  c.h = __float2bfloat16(f);
  return c.u;
}

// ---------------- prep kernel 1: deterministic f64 abs-mean -> scales --------
__global__ void absmean_kernel(const float* __restrict__ W1,
                               const float* __restrict__ W2,
                               double* __restrict__ dscales,
                               float* __restrict__ fscales) {
  const float* W = blockIdx.x ? W2 : W1;
  const int N = D_HID * D_IN;  // 131072 for both tensors
  double s = 0.0;
  for (int i = threadIdx.x; i < N; i += 1024) s += (double)fabsf(W[i]);
  __shared__ double red[1024];
  red[threadIdx.x] = s;
  __syncthreads();
  for (int st = 512; st > 0; st >>= 1) {
    if (threadIdx.x < st) red[threadIdx.x] += red[threadIdx.x + st];
    __syncthreads();
  }
  if (threadIdx.x == 0) {
    double sc = 1.47 * (red[0] / (double)N) + 1e-8;
    dscales[blockIdx.x] = sc;
    fscales[blockIdx.x] = (float)sc;
  }
}

// ---------------- prep kernel 2: quantize codes (exact ints in bf16) ---------
__global__ void quant_kernel(const float* __restrict__ W1,
                             const float* __restrict__ W2,
                             const double* __restrict__ dscales,
                             unsigned short* __restrict__ w1c,
                             unsigned short* __restrict__ w2c) {
  int idx = blockIdx.x * blockDim.x + threadIdx.x;  // 65536 float4 chunks total
  bool is2 = idx >= 32768;
  const float4* src = is2 ? (const float4*)W2 : (const float4*)W1;
  us4* dst = is2 ? (us4*)w2c : (us4*)w1c;
  int i = is2 ? idx - 32768 : idx;
  double s = dscales[is2 ? 1 : 0];
  float4 v = src[i];
  us4 o;
  // round-half-even in f64 to match a float64 numpy reference at boundaries
  o.x = f2bf((float)fmin(fmax(rint((double)v.x / s), -2.0), 1.0));
  o.y = f2bf((float)fmin(fmax(rint((double)v.y / s), -2.0), 1.0));
  o.z = f2bf((float)fmin(fmax(rint((double)v.z / s), -2.0), 1.0));
  o.w = f2bf((float)fmin(fmax(rint((double)v.w / s), -2.0), 1.0));
  dst[i] = o;
}

// ---------------- fused MLP kernel ------------------------------------------
// Block: 256 threads (4 waves), BM=64 batch rows.
// LDS: h tile [64][512] bf16 (64KB); x tile [64][256] bf16 aliases first 32KB.
// Layer 1: h^T = W1c(512x256) * x^T(256x64); wave wv owns hidden rows [128wv,128wv+128)
// Layer 2: out^T = W2c(256x512) * h^T(512x64); wave wv owns out cols [64wv,64wv+64)
__launch_bounds__(256, 2)
__global__ void fused_mlp(const float* __restrict__ x,
                          const float* __restrict__ b1,
                          const float* __restrict__ b2,
                          const unsigned short* __restrict__ w1c,
                          const unsigned short* __restrict__ w2c,
                          const float* __restrict__ fscales,
                          float* __restrict__ out) {
  __shared__ unsigned short lds[BM * D_HID];  // 64 KB
  const int t = threadIdx.x;
  const int lane = t & 63;
  const int wv = t >> 6;      // wave id 0..3
  const int l15 = lane & 15;
  const int g = lane >> 4;    // 0..3 (k-slot group)
  const long row0 = (long)blockIdx.x * BM;

  // ---- stage x tile: [64][256] f32 -> bf16, XOR-swizzled rows (T2/G4)
  // swizzle: within a row (32 slots of 16B), slot ^= (row & 7)
  {
    const float4* xsrc = (const float4*)(x + row0 * D_IN);
#pragma unroll
    for (int i = 0; i < 16; ++i) {
      int chunk = i * 256 + t;        // 4096 float4 chunks, coalesced
      int m = chunk >> 6;             // 64 float4 per row
      int c4 = chunk & 63;
      float4 v = xsrc[chunk];
      int slot = (c4 >> 1) ^ (m & 7);
      us4 o;
      o.x = f2bf(v.x); o.y = f2bf(v.y); o.z = f2bf(v.z); o.w = f2bf(v.w);
      *(us4*)&lds[m * 256 + slot * 8 + (c4 & 1) * 4] = o;
    }
  }
  float s1 = fscales[0];
  float s2 = fscales[1];
  __syncthreads();

  // ---- layer 1 K-loop (K=256, 8 steps of 32)
  f32x4 zero4 = {0.f, 0.f, 0.f, 0.f};
  f32x4 acc1[8][4];
#pragma unroll
  for (int a = 0; a < 8; ++a)
#pragma unroll
    for (int b = 0; b < 4; ++b) acc1[a][b] = zero4;

#pragma unroll
  for (int kk = 0; kk < 8; ++kk) {
    bf16x8 bx[4];  // B-frags: x^T, col m = 16nf+l15, k = kk*32 + g*8 .. +8
#pragma unroll
    for (int nf = 0; nf < 4; ++nf) {
      int m = nf * 16 + l15;
      int slot = (kk * 4 + g) ^ (m & 7);
      bx[nf] = *(const bf16x8*)&lds[m * 256 + slot * 8];
    }
#pragma unroll
    for (int mf = 0; mf < 8; ++mf) {
      int c = 128 * wv + 16 * mf + l15;  // W1 row (hidden dim)
      bf16x8 aw = *(const bf16x8*)&w1c[c * 256 + kk * 32 + g * 8];
#pragma unroll
      for (int nf = 0; nf < 4; ++nf)
        acc1[mf][nf] = __builtin_amdgcn_mfma_f32_16x16x32_bf16(aw, bx[nf], acc1[mf][nf], 0, 0, 0);
    }
  }
  __syncthreads();  // x reads done; h may overwrite the aliased region

  // ---- epilogue 1: h = relu(s1*acc + b1) -> bf16 -> LDS h[m][c] (swizzled)
  // D-frag: batch m = 16nf + l15 (col), hidden c = 128wv+16mf + g*4 + reg (row)
#pragma unroll
  for (int mf = 0; mf < 8; ++mf) {
    int cb = 128 * wv + 16 * mf + g * 4;
    float4 bb = *(const float4*)&b1[cb];
    int slot_base = cb >> 3;        // 64 slots of 16B per 1024B row
    int half = (g & 1) * 4;
#pragma unroll
    for (int nf = 0; nf < 4; ++nf) {
      int m = nf * 16 + l15;
      f32x4 a = acc1[mf][nf];
      us4 o;
      o.x = f2bf(fmaxf(s1 * a[0] + bb.x, 0.f));
      o.y = f2bf(fmaxf(s1 * a[1] + bb.y, 0.f));
      o.z = f2bf(fmaxf(s1 * a[2] + bb.z, 0.f));
      o.w = f2bf(fmaxf(s1 * a[3] + bb.w, 0.f));
      int slot = slot_base ^ (m & 7);
      *(us4*)&lds[m * 512 + slot * 8 + half] = o;
    }
  }
  __syncthreads();

  // ---- layer 2 K-loop (K=512, 16 steps of 32)
  f32x4 acc2[4][4];
#pragma unroll
  for (int a = 0; a < 4; ++a)
#pragma unroll
    for (int b = 0; b < 4; ++b) acc2[a][b] = zero4;

#pragma unroll
  for (int kk = 0; kk < 16; ++kk) {
    bf16x8 bh[4];  // B-frags from h LDS
#pragma unroll
    for (int nf = 0; nf < 4; ++nf) {
      int m = nf * 16 + l15;
      int slot = (kk * 4 + g) ^ (m & 7);
      bh[nf] = *(const bf16x8*)&lds[m * 512 + slot * 8];
    }
#pragma unroll
    for (int mf = 0; mf < 4; ++mf) {
      int n = 64 * wv + 16 * mf + l15;  // W2 row (out col)
      bf16x8 aw = *(const bf16x8*)&w2c[n * 512 + kk * 32 + g * 8];
#pragma unroll
      for (int nf = 0; nf < 4; ++nf)
        acc2[mf][nf] = __builtin_amdgcn_mfma_f32_16x16x32_bf16(aw, bh[nf], acc2[mf][nf], 0, 0, 0);
    }
  }

  // ---- epilogue 2: out[m][n] = s2*acc + b2[n], float4 stores
#pragma unroll
  for (int mf = 0; mf < 4; ++mf) {
    int nb = 64 * wv + 16 * mf + g * 4;
    float4 bb = *(const float4*)&b2[nb];
#pragma unroll
    for (int nf = 0; nf < 4; ++nf) {
      int m = nf * 16 + l15;
      f32x4 a = acc2[mf][nf];
      float4 o;
      o.x = s2 * a[0] + bb.x;
      o.y = s2 * a[1] + bb.y;
      o.z = s2 * a[2] + bb.z;
      o.w = s2 * a[3] + bb.w;
      *(float4*)&out[(row0 + m) * D_OUT + nb] = o;
    }
  }
}

extern "C" void kernel_launch(void* const* d_in, const int* in_sizes, int n_in,
                              void* d_out, int out_size, void* d_ws, size_t ws_size,
                              hipStream_t stream) {
  const float* x  = (const float*)d_in[0];
  const float* W1 = (const float*)d_in[1];
  const float* b1 = (const float*)d_in[2];
  const float* W2 = (const float*)d_in[3];
  const float* b2 = (const float*)d_in[4];
  float* out = (float*)d_out;

  // workspace layout: [0,16) f64 scales, [16,24) f32 scales, codes at 1024
  double* dsc = (double*)d_ws;
  float* fsc = (float*)((char*)d_ws + 16);
  unsigned short* w1c = (unsigned short*)((char*)d_ws + 1024);
  unsigned short* w2c = (unsigned short*)((char*)d_ws + 1024 + D_HID * D_IN * 2);

  int Brows = in_sizes[0] / D_IN;  // 262144

  absmean_kernel<<<dim3(2), dim3(1024), 0, stream>>>(W1, W2, dsc, fsc);
  quant_kernel<<<dim3(256), dim3(256), 0, stream>>>(W1, W2, dsc, w1c, w2c);
  fused_mlp<<<dim3(Brows / BM), dim3(256), 0, stream>>>(x, b1, b2, w1c, w2c, fsc, out);
}

// Round 2
// 332.584 us; speedup vs baseline: 1.1926x; 1.1926x over previous
//
#include <hip/hip_runtime.h>
#include <hip/hip_bf16.h>

// Problem: out = lecac_linear(relu(lecac_linear(x, W1, b1)), W2, b2)
//   x: [262144, 256] f32, W1: [512,256], b1: [512], W2: [256,512], b2: [256]
// Strategy: quantize weights to exact integer codes (bf16) once, then one fused
// MFMA kernel: h^T = W1q * x^T (h kept in LDS as bf16), out^T = W2q * h^T.
// R2: 512-thread blocks (8 waves) for 16 waves/CU (was 8) — latency-bound fix.

typedef __attribute__((ext_vector_type(8))) short bf16x8;
typedef __attribute__((ext_vector_type(4))) float f32x4;
typedef __attribute__((ext_vector_type(4))) unsigned short us4;

#define D_IN 256
#define D_HID 512
#define D_OUT 256
#define BM 64

__device__ __forceinline__ unsigned short f2bf(float f) {
  union { __hip_bfloat16 h; unsigned short u; } c;
  c.h = __float2bfloat16(f);
  return c.u;
}

// ---- prep 1: deterministic f64 partial abs-sums (8 chunks per tensor) ------
__global__ void partial_abs_kernel(const float* __restrict__ W1,
                                   const float* __restrict__ W2,
                                   double* __restrict__ part) {
  const int b = blockIdx.x;                 // 0..15
  const float* W = (b < 8) ? W1 : W2;
  const float* p = W + (b & 7) * 16384;     // 131072 / 8
  double s = 0.0;
  for (int i = threadIdx.x; i < 16384; i += 1024) s += (double)fabsf(p[i]);
  __shared__ double red[1024];
  red[threadIdx.x] = s;
  __syncthreads();
  for (int st = 512; st > 0; st >>= 1) {
    if (threadIdx.x < st) red[threadIdx.x] += red[threadIdx.x + st];
    __syncthreads();
  }
  if (threadIdx.x == 0) part[b] = red[0];
}

// ---- prep 2: quantize codes (exact ints in bf16); finalizes scales inline --
__global__ void quant_kernel(const float* __restrict__ W1,
                             const float* __restrict__ W2,
                             const double* __restrict__ part,
                             unsigned short* __restrict__ w1c,
                             unsigned short* __restrict__ w2c,
                             float* __restrict__ fscales) {
  int idx = blockIdx.x * blockDim.x + threadIdx.x;  // 65536 float4 chunks
  bool is2 = idx >= 32768;
  const float4* src = is2 ? (const float4*)W2 : (const float4*)W1;
  us4* dst = is2 ? (us4*)w2c : (us4*)w1c;
  int i = is2 ? idx - 32768 : idx;
  // deterministic fixed-order sum of the 8 partials for this tensor
  const double* pp = part + (is2 ? 8 : 0);
  double sum = ((pp[0] + pp[1]) + (pp[2] + pp[3])) + ((pp[4] + pp[5]) + (pp[6] + pp[7]));
  double s = 1.47 * (sum / 131072.0) + 1e-8;
  if (idx == 0) {
    const double* q = part;
    double s0 = 1.47 * ((((q[0]+q[1])+(q[2]+q[3]))+((q[4]+q[5])+(q[6]+q[7]))) / 131072.0) + 1e-8;
    double s1 = 1.47 * ((((q[8]+q[9])+(q[10]+q[11]))+((q[12]+q[13])+(q[14]+q[15]))) / 131072.0) + 1e-8;
    fscales[0] = (float)s0;
    fscales[1] = (float)s1;
  }
  float4 v = src[i];
  us4 o;
  // round-half-even in f64 to match the float64 numpy ref at boundaries
  o.x = f2bf((float)fmin(fmax(rint((double)v.x / s), -2.0), 1.0));
  o.y = f2bf((float)fmin(fmax(rint((double)v.y / s), -2.0), 1.0));
  o.z = f2bf((float)fmin(fmax(rint((double)v.z / s), -2.0), 1.0));
  o.w = f2bf((float)fmin(fmax(rint((double)v.w / s), -2.0), 1.0));
  dst[i] = o;
}

// ---------------- fused MLP kernel ------------------------------------------
// Block: 512 threads (8 waves), BM=64 batch rows.
// LDS: h tile [64][512] bf16 (64KB); x tile [64][256] bf16 aliases first 32KB.
// Layer 1: h^T = W1c(512x256) * x^T(256x64); wave wv owns hidden rows [64wv,64wv+64)
// Layer 2: out^T = W2c(256x512) * h^T(512x64); wave wv owns out cols [32wv,32wv+32)
__launch_bounds__(512, 4)
__global__ void fused_mlp(const float* __restrict__ x,
                          const float* __restrict__ b1,
                          const float* __restrict__ b2,
                          const unsigned short* __restrict__ w1c,
                          const unsigned short* __restrict__ w2c,
                          const float* __restrict__ fscales,
                          float* __restrict__ out) {
  __shared__ unsigned short lds[BM * D_HID];  // 64 KB
  const int t = threadIdx.x;
  const int lane = t & 63;
  const int wv = t >> 6;      // wave id 0..7
  const int l15 = lane & 15;
  const int g = lane >> 4;    // 0..3 (k-slot group)
  const long row0 = (long)blockIdx.x * BM;

  // ---- stage x tile: [64][256] f32 -> bf16, XOR-swizzled rows (T2/G4)
  // swizzle: within a row (32 slots of 16B), slot ^= (row & 7)
  {
    const float4* xsrc = (const float4*)(x + row0 * D_IN);
#pragma unroll
    for (int i = 0; i < 8; ++i) {
      int chunk = i * 512 + t;        // 4096 float4 chunks, coalesced
      int m = chunk >> 6;             // 64 float4 per row
      int c4 = chunk & 63;
      float4 v = xsrc[chunk];
      int slot = (c4 >> 1) ^ (m & 7);
      us4 o;
      o.x = f2bf(v.x); o.y = f2bf(v.y); o.z = f2bf(v.z); o.w = f2bf(v.w);
      *(us4*)&lds[m * 256 + slot * 8 + (c4 & 1) * 4] = o;
    }
  }
  float s1 = fscales[0];
  float s2 = fscales[1];
  __syncthreads();

  // ---- layer 1 K-loop (K=256, 8 steps of 32)
  f32x4 zero4 = {0.f, 0.f, 0.f, 0.f};
  f32x4 acc1[4][4];
#pragma unroll
  for (int a = 0; a < 4; ++a)
#pragma unroll
    for (int b = 0; b < 4; ++b) acc1[a][b] = zero4;

#pragma unroll
  for (int kk = 0; kk < 8; ++kk) {
    bf16x8 bx[4];  // B-frags: x^T, col m = 16nf+l15, k = kk*32 + g*8 .. +8
#pragma unroll
    for (int nf = 0; nf < 4; ++nf) {
      int m = nf * 16 + l15;
      int slot = (kk * 4 + g) ^ (m & 7);
      bx[nf] = *(const bf16x8*)&lds[m * 256 + slot * 8];
    }
#pragma unroll
    for (int mf = 0; mf < 4; ++mf) {
      int c = 64 * wv + 16 * mf + l15;  // W1 row (hidden dim)
      bf16x8 aw = *(const bf16x8*)&w1c[c * 256 + kk * 32 + g * 8];
#pragma unroll
      for (int nf = 0; nf < 4; ++nf)
        acc1[mf][nf] = __builtin_amdgcn_mfma_f32_16x16x32_bf16(aw, bx[nf], acc1[mf][nf], 0, 0, 0);
    }
  }
  __syncthreads();  // x reads done; h may overwrite the aliased region

  // ---- epilogue 1: h = relu(s1*acc + b1) -> bf16 -> LDS h[m][c] (swizzled)
  // D-frag: batch m = 16nf + l15 (col), hidden c = 64wv+16mf + g*4 + reg (row)
#pragma unroll
  for (int mf = 0; mf < 4; ++mf) {
    int cb = 64 * wv + 16 * mf + g * 4;
    float4 bb = *(const float4*)&b1[cb];
    int slot_base = cb >> 3;        // 64 slots of 16B per 1024B row
    int half = (g & 1) * 4;
#pragma unroll
    for (int nf = 0; nf < 4; ++nf) {
      int m = nf * 16 + l15;
      f32x4 a = acc1[mf][nf];
      us4 o;
      o.x = f2bf(fmaxf(s1 * a[0] + bb.x, 0.f));
      o.y = f2bf(fmaxf(s1 * a[1] + bb.y, 0.f));
      o.z = f2bf(fmaxf(s1 * a[2] + bb.z, 0.f));
      o.w = f2bf(fmaxf(s1 * a[3] + bb.w, 0.f));
      int slot = slot_base ^ (m & 7);
      *(us4*)&lds[m * 512 + slot * 8 + half] = o;
    }
  }
  __syncthreads();

  // ---- layer 2 K-loop (K=512, 16 steps of 32)
  f32x4 acc2[2][4];
#pragma unroll
  for (int a = 0; a < 2; ++a)
#pragma unroll
    for (int b = 0; b < 4; ++b) acc2[a][b] = zero4;

#pragma unroll
  for (int kk = 0; kk < 16; ++kk) {
    bf16x8 bh[4];  // B-frags from h LDS
#pragma unroll
    for (int nf = 0; nf < 4; ++nf) {
      int m = nf * 16 + l15;
      int slot = (kk * 4 + g) ^ (m & 7);
      bh[nf] = *(const bf16x8*)&lds[m * 512 + slot * 8];
    }
#pragma unroll
    for (int mf = 0; mf < 2; ++mf) {
      int n = 32 * wv + 16 * mf + l15;  // W2 row (out col)
      bf16x8 aw = *(const bf16x8*)&w2c[n * 512 + kk * 32 + g * 8];
#pragma unroll
      for (int nf = 0; nf < 4; ++nf)
        acc2[mf][nf] = __builtin_amdgcn_mfma_f32_16x16x32_bf16(aw, bh[nf], acc2[mf][nf], 0, 0, 0);
    }
  }

  // ---- epilogue 2: out[m][n] = s2*acc + b2[n], float4 stores
#pragma unroll
  for (int mf = 0; mf < 2; ++mf) {
    int nb = 32 * wv + 16 * mf + g * 4;
    float4 bb = *(const float4*)&b2[nb];
#pragma unroll
    for (int nf = 0; nf < 4; ++nf) {
      int m = nf * 16 + l15;
      f32x4 a = acc2[mf][nf];
      float4 o;
      o.x = s2 * a[0] + bb.x;
      o.y = s2 * a[1] + bb.y;
      o.z = s2 * a[2] + bb.z;
      o.w = s2 * a[3] + bb.w;
      *(float4*)&out[(row0 + m) * D_OUT + nb] = o;
    }
  }
}

extern "C" void kernel_launch(void* const* d_in, const int* in_sizes, int n_in,
                              void* d_out, int out_size, void* d_ws, size_t ws_size,
                              hipStream_t stream) {
  const float* x  = (const float*)d_in[0];
  const float* W1 = (const float*)d_in[1];
  const float* b1 = (const float*)d_in[2];
  const float* W2 = (const float*)d_in[3];
  const float* b2 = (const float*)d_in[4];
  float* out = (float*)d_out;

  // workspace layout: [0,128) f64 partials (16), [128,136) f32 scales, codes at 1024
  double* part = (double*)d_ws;
  float* fsc = (float*)((char*)d_ws + 128);
  unsigned short* w1c = (unsigned short*)((char*)d_ws + 1024);
  unsigned short* w2c = (unsigned short*)((char*)d_ws + 1024 + D_HID * D_IN * 2);

  int Brows = in_sizes[0] / D_IN;  // 262144

  partial_abs_kernel<<<dim3(16), dim3(1024), 0, stream>>>(W1, W2, part);
  quant_kernel<<<dim3(256), dim3(256), 0, stream>>>(W1, W2, part, w1c, w2c, fsc);
  fused_mlp<<<dim3(Brows / BM), dim3(512), 0, stream>>>(x, b1, b2, w1c, w2c, fsc, out);
}

// Round 3
// 326.916 us; speedup vs baseline: 1.2132x; 1.0173x over previous
//
#include <hip/hip_runtime.h>
#include <hip/hip_bf16.h>

// Problem: out = lecac_linear(relu(lecac_linear(x, W1, b1)), W2, b2)
//   x: [262144, 256] f32, W1: [512,256], b1: [512], W2: [256,512], b2: [256]
// Strategy: quantize weights to exact integer codes (bf16) once, then one fused
// MFMA kernel: h^T = W1q * x^T (h kept in LDS as bf16), out^T = W2q * h^T.
// R3: 1024-thread blocks, halved per-wave tiles + explicit depth-2 register
// prefetch of weight fragments (R2 was VGPR-capped at 128 -> no pipelining ->
// exposed L2 latency every K-step with all pipes <20% busy).

typedef __attribute__((ext_vector_type(8))) short bf16x8;
typedef __attribute__((ext_vector_type(4))) float f32x4;
typedef __attribute__((ext_vector_type(4))) unsigned short us4;

#define D_IN 256
#define D_HID 512
#define D_OUT 256
#define BM 64

__device__ __forceinline__ unsigned short f2bf(float f) {
  union { __hip_bfloat16 h; unsigned short u; } c;
  c.h = __float2bfloat16(f);
  return c.u;
}

// ---- prep 1: deterministic f64 partial abs-sums (8 chunks per tensor) ------
__global__ void partial_abs_kernel(const float* __restrict__ W1,
                                   const float* __restrict__ W2,
                                   double* __restrict__ part) {
  const int b = blockIdx.x;                 // 0..15
  const float* W = (b < 8) ? W1 : W2;
  const float* p = W + (b & 7) * 16384;     // 131072 / 8
  double s = 0.0;
  for (int i = threadIdx.x; i < 16384; i += 1024) s += (double)fabsf(p[i]);
  __shared__ double red[1024];
  red[threadIdx.x] = s;
  __syncthreads();
  for (int st = 512; st > 0; st >>= 1) {
    if (threadIdx.x < st) red[threadIdx.x] += red[threadIdx.x + st];
    __syncthreads();
  }
  if (threadIdx.x == 0) part[b] = red[0];
}

// ---- prep 2: quantize codes (exact ints in bf16); finalizes scales inline --
__global__ void quant_kernel(const float* __restrict__ W1,
                             const float* __restrict__ W2,
                             const double* __restrict__ part,
                             unsigned short* __restrict__ w1c,
                             unsigned short* __restrict__ w2c,
                             float* __restrict__ fscales) {
  int idx = blockIdx.x * blockDim.x + threadIdx.x;  // 65536 float4 chunks
  bool is2 = idx >= 32768;
  const float4* src = is2 ? (const float4*)W2 : (const float4*)W1;
  us4* dst = is2 ? (us4*)w2c : (us4*)w1c;
  int i = is2 ? idx - 32768 : idx;
  const double* pp = part + (is2 ? 8 : 0);
  double sum = ((pp[0] + pp[1]) + (pp[2] + pp[3])) + ((pp[4] + pp[5]) + (pp[6] + pp[7]));
  double s = 1.47 * (sum / 131072.0) + 1e-8;
  if (idx == 0) {
    const double* q = part;
    double s0 = 1.47 * ((((q[0]+q[1])+(q[2]+q[3]))+((q[4]+q[5])+(q[6]+q[7]))) / 131072.0) + 1e-8;
    double s1 = 1.47 * ((((q[8]+q[9])+(q[10]+q[11]))+((q[12]+q[13])+(q[14]+q[15]))) / 131072.0) + 1e-8;
    fscales[0] = (float)s0;
    fscales[1] = (float)s1;
  }
  float4 v = src[i];
  us4 o;
  o.x = f2bf((float)fmin(fmax(rint((double)v.x / s), -2.0), 1.0));
  o.y = f2bf((float)fmin(fmax(rint((double)v.y / s), -2.0), 1.0));
  o.z = f2bf((float)fmin(fmax(rint((double)v.z / s), -2.0), 1.0));
  o.w = f2bf((float)fmin(fmax(rint((double)v.w / s), -2.0), 1.0));
  dst[i] = o;
}

// ---------------- fused MLP kernel ------------------------------------------
// Block: 1024 threads (16 waves), BM=64 batch rows, 64KB LDS (x aliases h).
// L1: h^T = W1c(512x256) * x^T(256x64); wave wv owns hidden rows [32wv,32wv+32)
// L2: out^T = W2c(256x512) * h^T(512x64); wave wv owns out cols [16wv,16wv+16)
__launch_bounds__(1024, 4)
__global__ void fused_mlp(const float* __restrict__ x,
                          const float* __restrict__ b1,
                          const float* __restrict__ b2,
                          const unsigned short* __restrict__ w1c,
                          const unsigned short* __restrict__ w2c,
                          const float* __restrict__ fscales,
                          float* __restrict__ out) {
  __shared__ unsigned short lds[BM * D_HID];  // 64 KB; x tile aliases first 32KB
  const int t = threadIdx.x;
  const int lane = t & 63;
  const int wv = t >> 6;      // wave id 0..15
  const int l15 = lane & 15;
  const int g = lane >> 4;    // 0..3 (k-slot group)
  const long row0 = (long)blockIdx.x * BM;

  const unsigned short* w1p = w1c + (32 * wv + l15) * 256 + g * 8;  // +4096/mf, +32/kk
  const unsigned short* w2p = w2c + (16 * wv + l15) * 512 + g * 8;  // +32/kk

  // ---- prefetch L1 weight frags for kk=0,1 (L2-resident; fly during x-stage)
  bf16x8 aw[2][2];  // [kk parity][mf]
  aw[0][0] = *(const bf16x8*)(w1p);
  aw[0][1] = *(const bf16x8*)(w1p + 4096);
  aw[1][0] = *(const bf16x8*)(w1p + 32);
  aw[1][1] = *(const bf16x8*)(w1p + 4096 + 32);

  // ---- stage x tile: [64][256] f32 -> bf16, XOR-swizzled (slot ^= row&7)
  {
    const float4* xsrc = (const float4*)(x + row0 * D_IN);
#pragma unroll
    for (int i = 0; i < 4; ++i) {
      int chunk = i * 1024 + t;       // 4096 float4 chunks, coalesced
      int m = chunk >> 6;
      int c4 = chunk & 63;
      float4 v = xsrc[chunk];
      int slot = (c4 >> 1) ^ (m & 7);
      us4 o;
      o.x = f2bf(v.x); o.y = f2bf(v.y); o.z = f2bf(v.z); o.w = f2bf(v.w);
      *(us4*)&lds[m * 256 + slot * 8 + (c4 & 1) * 4] = o;
    }
  }
  float s1 = fscales[0];
  float s2 = fscales[1];
  __syncthreads();

  // ---- layer 1 K-loop (K=256, 8 steps of 32), SW-pipelined
  f32x4 zero4 = {0.f, 0.f, 0.f, 0.f};
  f32x4 acc1[2][4];
#pragma unroll
  for (int a = 0; a < 2; ++a)
#pragma unroll
    for (int b = 0; b < 4; ++b) acc1[a][b] = zero4;

  bf16x8 bx[2][4];  // [kk parity][nf]
#pragma unroll
  for (int nf = 0; nf < 4; ++nf) {
    int m = nf * 16 + l15;
    int slot = g ^ (m & 7);
    bx[0][nf] = *(const bf16x8*)&lds[m * 256 + slot * 8];
  }

#pragma unroll
  for (int kk = 0; kk < 8; ++kk) {
    bf16x8 a0 = aw[kk & 1][0];
    bf16x8 a1 = aw[kk & 1][1];
    if (kk + 2 < 8) {
      aw[kk & 1][0] = *(const bf16x8*)(w1p + (kk + 2) * 32);
      aw[kk & 1][1] = *(const bf16x8*)(w1p + 4096 + (kk + 2) * 32);
    }
    if (kk + 1 < 8) {
#pragma unroll
      for (int nf = 0; nf < 4; ++nf) {
        int m = nf * 16 + l15;
        int slot = ((kk + 1) * 4 + g) ^ (m & 7);
        bx[(kk + 1) & 1][nf] = *(const bf16x8*)&lds[m * 256 + slot * 8];
      }
    }
#pragma unroll
    for (int nf = 0; nf < 4; ++nf) {
      acc1[0][nf] = __builtin_amdgcn_mfma_f32_16x16x32_bf16(a0, bx[kk & 1][nf], acc1[0][nf], 0, 0, 0);
      acc1[1][nf] = __builtin_amdgcn_mfma_f32_16x16x32_bf16(a1, bx[kk & 1][nf], acc1[1][nf], 0, 0, 0);
    }
  }
  __syncthreads();  // x reads done; h may overwrite the aliased region

  // ---- epilogue 1: h = relu(s1*acc + b1) -> bf16 -> LDS h[m][c] (swizzled)
#pragma unroll
  for (int mf = 0; mf < 2; ++mf) {
    int cb = 32 * wv + 16 * mf + g * 4;
    float4 bb = *(const float4*)&b1[cb];
    int slot_base = cb >> 3;
    int half = (g & 1) * 4;
#pragma unroll
    for (int nf = 0; nf < 4; ++nf) {
      int m = nf * 16 + l15;
      f32x4 a = acc1[mf][nf];
      us4 o;
      o.x = f2bf(fmaxf(s1 * a[0] + bb.x, 0.f));
      o.y = f2bf(fmaxf(s1 * a[1] + bb.y, 0.f));
      o.z = f2bf(fmaxf(s1 * a[2] + bb.z, 0.f));
      o.w = f2bf(fmaxf(s1 * a[3] + bb.w, 0.f));
      int slot = slot_base ^ (m & 7);
      *(us4*)&lds[m * 512 + slot * 8 + half] = o;
    }
  }
  // prefetch L2 weight frags for kk=0,1 while epi1 stores land
  bf16x8 aw2[2];
  aw2[0] = *(const bf16x8*)(w2p);
  aw2[1] = *(const bf16x8*)(w2p + 32);
  __syncthreads();

  // ---- layer 2 K-loop (K=512, 16 steps of 32), SW-pipelined
  f32x4 acc2[4];
#pragma unroll
  for (int b = 0; b < 4; ++b) acc2[b] = zero4;

  bf16x8 bh[2][4];
#pragma unroll
  for (int nf = 0; nf < 4; ++nf) {
    int m = nf * 16 + l15;
    int slot = g ^ (m & 7);
    bh[0][nf] = *(const bf16x8*)&lds[m * 512 + slot * 8];
  }

#pragma unroll
  for (int kk = 0; kk < 16; ++kk) {
    bf16x8 a0 = aw2[kk & 1];
    if (kk + 2 < 16) aw2[kk & 1] = *(const bf16x8*)(w2p + (kk + 2) * 32);
    if (kk + 1 < 16) {
#pragma unroll
      for (int nf = 0; nf < 4; ++nf) {
        int m = nf * 16 + l15;
        int slot = ((kk + 1) * 4 + g) ^ (m & 7);
        bh[(kk + 1) & 1][nf] = *(const bf16x8*)&lds[m * 512 + slot * 8];
      }
    }
#pragma unroll
    for (int nf = 0; nf < 4; ++nf)
      acc2[nf] = __builtin_amdgcn_mfma_f32_16x16x32_bf16(a0, bh[kk & 1][nf], acc2[nf], 0, 0, 0);
  }

  // ---- epilogue 2: out[m][n] = s2*acc + b2[n], float4 stores
  {
    int nb = 16 * wv + g * 4;
    float4 bb = *(const float4*)&b2[nb];
#pragma unroll
    for (int nf = 0; nf < 4; ++nf) {
      int m = nf * 16 + l15;
      f32x4 a = acc2[nf];
      float4 o;
      o.x = s2 * a[0] + bb.x;
      o.y = s2 * a[1] + bb.y;
      o.z = s2 * a[2] + bb.z;
      o.w = s2 * a[3] + bb.w;
      *(float4*)&out[(row0 + m) * D_OUT + nb] = o;
    }
  }
}

extern "C" void kernel_launch(void* const* d_in, const int* in_sizes, int n_in,
                              void* d_out, int out_size, void* d_ws, size_t ws_size,
                              hipStream_t stream) {
  const float* x  = (const float*)d_in[0];
  const float* W1 = (const float*)d_in[1];
  const float* b1 = (const float*)d_in[2];
  const float* W2 = (const float*)d_in[3];
  const float* b2 = (const float*)d_in[4];
  float* out = (float*)d_out;

  // workspace layout: [0,128) f64 partials (16), [128,136) f32 scales, codes at 1024
  double* part = (double*)d_ws;
  float* fsc = (float*)((char*)d_ws + 128);
  unsigned short* w1c = (unsigned short*)((char*)d_ws + 1024);
  unsigned short* w2c = (unsigned short*)((char*)d_ws + 1024 + D_HID * D_IN * 2);

  int Brows = in_sizes[0] / D_IN;  // 262144

  partial_abs_kernel<<<dim3(16), dim3(1024), 0, stream>>>(W1, W2, part);
  quant_kernel<<<dim3(256), dim3(256), 0, stream>>>(W1, W2, part, w1c, w2c, fsc);
  fused_mlp<<<dim3(Brows / BM), dim3(1024), 0, stream>>>(x, b1, b2, w1c, w2c, fsc, out);
}